// Round 5
// baseline (501.452 us; speedup 1.0000x reference)
//
#include <hip/hip_runtime.h>
#include <stdint.h>
#include <math.h>

#define N_CLS    81
#define TOPK     1000
#define LISTCAP  (1u << 21)     // 2M candidate keys (16 MB)
#define CAP2     65536          // coarse-selected capacity
#define CANDCAP  3072           // exact-threshold candidates held in LDS
#define SCORE_TH 0.05f
#define IMG_W    1333.0f
#define IMG_H    800.0f
#define GH_REP   16             // coarse-hist replicas (atomic spread)

// coarse bucket = float_bits >> 19; ghist index = (bits>>19) - GH_BASE in [0,128)
#define GH_BASE  1905

// workspace layout (byte offsets)
#define OFF_CNT    0                       // u32 total candidates
#define OFF_CNT2   4                       // u32 coarse-selected count
#define OFF_DONE   8                       // u32 select done-counter
#define OFF_DONE2  12                      // u32 conflict done-counter
#define OFF_GH     64                      // u32[GH_REP][128] coarse hist (8192 B)
#define OFF_RH     8256                    // u32[1024] refined hist
#define MEMSET_BYTES 12352
#define OFF_SEL    12352                   // u64[LISTCAP]
#define OFF_SEL2   16789568                // u64[CAP2]
#define OFF_BOX    17313856                // f32[1000*4]
#define OFF_SCORE  17329856                // f32[1000]
#define OFF_CLS    17333856                // i32[1000]
#define OFF_MASK   17337856                // u64[1000..1024 x 16] conflict bit matrix

typedef unsigned long long u64;

// ------- K1: single pass: softmax, coarse hist (LDS), compact all p>0.05 -------
// NOTE: score arithmetic (lane mapping, butterfly order, expf, e/s) must stay
// bit-identical to rounds 1-4 (absmax 0.0). Only the LOAD PATH changed:
// float4 global -> LDS stage -> same per-lane values.
__global__ __launch_bounds__(256) void k_pass1(
        const float* __restrict__ logits, int nrows,
        u64* __restrict__ sel, unsigned* __restrict__ cnt,
        unsigned* __restrict__ ghist) {
    __shared__ unsigned lh[128];
    __shared__ u64 cbuf[1024];
    __shared__ __align__(16) float stage[4][328];   // per-wave 4-row stage (324 used)
    __shared__ unsigned lcnt, gbase;
    int tid = threadIdx.x, wv = tid >> 6, ln = tid & 63;
    for (int i = tid; i < 128; i += 256) lh[i] = 0;
    if (tid == 0) lcnt = 0;
    __syncthreads();

    int stride = gridDim.x * 16;
    for (int base = blockIdx.x * 16 + wv * 4; base < nrows; base += stride) {
        int nr = nrows - base; if (nr > 4) nr = 4;   // wave-uniform
        float v0[4], v1[4], m[4], e0[4], e1[4], s[4];
        if (nr == 4) {
            // 4 consecutive rows = 324 floats = 81 float4 (base%4==0 -> 16B aligned)
            const float4* rp4 = (const float4*)(logits + (size_t)base * N_CLS);
            float4 a = rp4[ln];
            float4 b;
            if (ln < 17) b = rp4[64 + ln];
            *((float4*)&stage[wv][ln * 4]) = a;
            if (ln < 17) *((float4*)&stage[wv][256 + ln * 4]) = b;
            __builtin_amdgcn_wave_barrier();   // pin ds_write before ds_read
            #pragma unroll
            for (int k = 0; k < 4; k++) {
                v0[k] = stage[wv][k * 81 + ln];
                v1[k] = (ln < N_CLS - 64) ? stage[wv][k * 81 + 64 + ln] : -INFINITY;
            }
        } else {
            #pragma unroll
            for (int k = 0; k < 4; k++) {
                bool ok = (k < nr);
                const float* rp = logits + (size_t)(ok ? base + k : base) * N_CLS;
                v0[k] = ok ? rp[ln] : 0.0f;
                v1[k] = (ok && ln < N_CLS - 64) ? rp[64 + ln] : -INFINITY;
            }
        }
        #pragma unroll
        for (int k = 0; k < 4; k++) m[k] = fmaxf(v0[k], v1[k]);
        #pragma unroll
        for (int off = 32; off > 0; off >>= 1)
            #pragma unroll
            for (int k = 0; k < 4; k++) m[k] = fmaxf(m[k], __shfl_xor(m[k], off));
        #pragma unroll
        for (int k = 0; k < 4; k++) {
            e0[k] = expf(v0[k] - m[k]);
            e1[k] = (ln < N_CLS - 64) ? expf(v1[k] - m[k]) : 0.0f;
            s[k] = e0[k] + e1[k];
        }
        #pragma unroll
        for (int off = 32; off > 0; off >>= 1)
            #pragma unroll
            for (int k = 0; k < 4; k++) s[k] += __shfl_xor(s[k], off);

        #pragma unroll
        for (int k = 0; k < 4; k++) {
            if (k >= nr) break;                     // wave-uniform
            float p0 = e0[k] / s[k];
            float p1 = e1[k] / s[k];
            bool c0 = (ln != 0) && (p0 > SCORE_TH);
            bool c1 = (ln < N_CLS - 64) && (p1 > SCORE_TH);
            unsigned fb0 = __float_as_uint(p0), fb1 = __float_as_uint(p1);
            if (c0) atomicAdd(&lh[(fb0 >> 19) - GH_BASE], 1u);
            if (c1) atomicAdd(&lh[(fb1 >> 19) - GH_BASE], 1u);
            u64 b0 = __ballot(c0), b1 = __ballot(c1);
            int n0 = __popcll(b0), n1 = __popcll(b1);
            if (n0 + n1 == 0) continue;
            unsigned wb = 0;
            if (ln == 0) wb = atomicAdd(&lcnt, (unsigned)(n0 + n1));
            wb = __shfl(wb, 0);
            u64 lt = (1ull << ln) - 1ull;
            unsigned flat = (unsigned)(base + k) * N_CLS + (unsigned)ln;
            if (c0) {
                unsigned pos = wb + (unsigned)__popcll(b0 & lt);
                u64 key = ((u64)fb0 << 32) | (u64)(0xFFFFFFu - flat);
                if (pos < 1024) cbuf[pos] = key;
                else { unsigned gp = atomicAdd(cnt, 1u); if (gp < LISTCAP) sel[gp] = key; }
            }
            if (c1) {
                unsigned pos = wb + (unsigned)n0 + (unsigned)__popcll(b1 & lt);
                u64 key = ((u64)fb1 << 32) | (u64)(0xFFFFFFu - (flat + 64u));
                if (pos < 1024) cbuf[pos] = key;
                else { unsigned gp = atomicAdd(cnt, 1u); if (gp < LISTCAP) sel[gp] = key; }
            }
        }
    }
    __syncthreads();
    unsigned* gh = ghist + (blockIdx.x & (GH_REP - 1)) * 128;
    for (int i = tid; i < 128; i += 256) {
        unsigned v = lh[i];
        if (v) atomicAdd(&gh[i], v);
    }
    unsigned total = lcnt; if (total > 1024u) total = 1024u;
    if (tid == 0) gbase = atomicAdd(cnt, total);
    __syncthreads();
    unsigned gb = gbase;
    for (unsigned i = tid; i < total; i += 256) {
        unsigned gp = gb + i;
        if (gp < LISTCAP) sel[gp] = cbuf[i];
    }
}

// ------- K2: coarse select + refined hist; LAST block finishes:
//             exact threshold -> filter -> rank -> decode to boxK/scoreK/clsK -------
__global__ __launch_bounds__(256) void k_select(
        const u64* __restrict__ sel, const unsigned* __restrict__ cnt,
        const unsigned* __restrict__ ghist, unsigned* __restrict__ rhist,
        u64* __restrict__ sel2, unsigned* __restrict__ cnt2,
        unsigned* __restrict__ done, const float* __restrict__ boxes,
        float* __restrict__ boxK, float* __restrict__ scoreK, int* __restrict__ clsK) {
    __shared__ unsigned lh[1024];
    __shared__ unsigned sa[256], sb_[256];
    __shared__ int sB, sG;
    __shared__ unsigned misc;
    __shared__ u64 cand[CANDCAP];
    __shared__ u64 sortedL[TOPK];
    int tid = threadIdx.x, ln = tid & 63;

    // ---- coarse bucket B from replicated global hist ----
    for (int i = tid; i < 1024; i += 256) lh[i] = 0;
    if (tid < 128) {
        unsigned c = 0;
        #pragma unroll
        for (int r = 0; r < GH_REP; r++) c += ghist[r * 128 + tid];
        sa[tid] = c;
    }
    if (tid == 0) sB = -1;
    __syncthreads();
    unsigned *s0 = sa, *s1 = sb_;
    for (int off = 1; off < 128; off <<= 1) {
        if (tid < 128) s1[tid] = s0[tid] + ((tid + off < 128) ? s0[tid + off] : 0u);
        __syncthreads();
        unsigned* t = s0; s0 = s1; s1 = t;
    }
    if (tid < 128 && s0[tid] >= TOPK) atomicMax(&sB, tid);
    __syncthreads();
    int B = sB;
    unsigned c_above = (B >= 0 && B < 127) ? s0[B + 1] : 0u;
    unsigned tbc = (B >= 0) ? ((unsigned)(B + GH_BASE) << 19) : 0u;
    unsigned Bb = (unsigned)(B + GH_BASE);
    __syncthreads();

    // ---- scan candidate list: coarse select + refined hist ----
    unsigned M = *cnt; if (M > LISTCAP) M = LISTCAP;
    unsigned gstride = gridDim.x * 256u;
    for (unsigned ib = blockIdx.x * 256u; ib < M; ib += gstride) {
        unsigned i = ib + tid;
        bool act = (i < M);
        u64 key = act ? sel[i] : 0ull;
        unsigned bits = (unsigned)(key >> 32);
        bool c = act && (bits >= tbc);
        if (c && B >= 0 && (bits >> 19) == Bb)
            atomicAdd(&lh[(bits >> 9) & 1023u], 1u);
        u64 bal = __ballot(c);
        int n = __popcll(bal);
        if (n) {
            unsigned wb = 0;
            if (ln == 0) wb = atomicAdd(cnt2, (unsigned)n);
            wb = __shfl(wb, 0);
            if (c) {
                unsigned pos = wb + (unsigned)__popcll(bal & ((1ull << ln) - 1ull));
                if (pos < CAP2) sel2[pos] = key;
            }
        }
    }
    __syncthreads();
    for (int i = tid; i < 1024; i += 256) {
        unsigned v = lh[i];
        if (v) atomicAdd(&rhist[i], v);
    }
    __threadfence();
    __syncthreads();
    if (tid == 0) misc = atomicAdd(done, 1u);
    __syncthreads();
    if (misc != gridDim.x - 1) return;
    // ================= finisher (last block only) =================
    __threadfence();

    // exact threshold tb from refined hist
    if (tid == 0) sG = -1;
    unsigned ps = 0;
    #pragma unroll
    for (int k = 0; k < 4; k++) ps += rhist[tid * 4 + k];
    sa[tid] = ps;
    __syncthreads();
    s0 = sa; s1 = sb_;
    for (int off = 1; off < 256; off <<= 1) {
        s1[tid] = s0[tid] + ((tid + off < 256) ? s0[tid + off] : 0u);
        __syncthreads();
        unsigned* t = s0; s0 = s1; s1 = t;
    }
    if (B >= 0 && c_above + s0[tid] >= TOPK) atomicMax(&sG, tid);
    __syncthreads();
    if (tid == 0) {
        unsigned tb = 0;
        if (B >= 0) {
            int g = sG;
            int sbin = 0;
            if (g >= 0) {
                unsigned cab = c_above + ((g < 255) ? s0[g + 1] : 0u);
                for (int i = g * 4 + 3; i >= g * 4; --i) {
                    unsigned c = rhist[i];
                    if (cab + c >= TOPK) { sbin = i; break; }
                    cab += c;
                }
            }
            tb = ((unsigned)(B + GH_BASE) << 19) | ((unsigned)sbin << 9);
        }
        misc = tb;
    }
    __syncthreads();
    unsigned tb = misc;
    __syncthreads();

    // filter keys >= tb into LDS cand
    unsigned S = *cnt2; if (S > CAP2) S = CAP2;
    if (tid == 0) misc = 0;
    __syncthreads();
    for (unsigned i = tid; i < S; i += 256) {
        u64 key = sel2[i];
        if ((unsigned)(key >> 32) >= tb) {
            unsigned p = atomicAdd(&misc, 1u);
            if (p < CANDCAP) cand[p] = key;
        }
    }
    for (int i = tid; i < TOPK; i += 256) sortedL[i] = 0ull;
    __syncthreads();
    unsigned C = misc; if (C > CANDCAP) C = CANDCAP;

    // rank by counting (keys distinct): one pass over cand, my-keys in regs
    u64 my[(CANDCAP + 255) / 256];
    unsigned r[(CANDCAP + 255) / 256];
    int nm = 0;
    for (unsigned t = tid; t < C; t += 256) { my[nm] = cand[t]; r[nm] = 0; nm++; }
    for (unsigned j = 0; j < C; j++) {
        u64 kj = cand[j];
        for (int q = 0; q < nm; q++) r[q] += (kj > my[q]) ? 1u : 0u;
    }
    for (int q = 0; q < nm; q++)
        if (r[q] < TOPK) sortedL[r[q]] = my[q];
    __syncthreads();

    // decode + clip to global boxK/scoreK/clsK
    for (int t = tid; t < TOPK; t += 256) {
        u64 key = sortedL[t];
        if (key != 0ull) {
            float sc = __uint_as_float((unsigned)(key >> 32));
            unsigned fi = 0xFFFFFFu - (unsigned)(key & 0xFFFFFFFFull);
            unsigned prop = fi / N_CLS;
            int cls = (int)(fi - prop * N_CLS);
            const float* bp = boxes + (size_t)prop * 4;
            boxK[t * 4 + 0] = fminf(fmaxf(bp[0], 0.0f), IMG_W - 1.0f);
            boxK[t * 4 + 1] = fminf(fmaxf(bp[1], 0.0f), IMG_H - 1.0f);
            boxK[t * 4 + 2] = fminf(fmaxf(bp[2], 0.0f), IMG_W - 1.0f);
            boxK[t * 4 + 3] = fminf(fmaxf(bp[3], 0.0f), IMG_H - 1.0f);
            scoreK[t] = sc;
            clsK[t] = cls;
        } else {
            boxK[t * 4 + 0] = 0.0f; boxK[t * 4 + 1] = 0.0f;
            boxK[t * 4 + 2] = 0.0f; boxK[t * 4 + 3] = 0.0f;
            scoreK[t] = 0.0f;
            clsK[t] = -1;
        }
    }
}

// ------- K3: conflict bit-matrix; LAST block runs greedy NMS + writes output -------
__global__ __launch_bounds__(1024) void k_conflict_nms(
        const float* __restrict__ boxK, const float* __restrict__ scoreK,
        const int* __restrict__ clsK, u64* __restrict__ mask,
        unsigned* __restrict__ done2, float* __restrict__ out) {
    __shared__ u64 words[16];
    __shared__ int changed;
    __shared__ unsigned lastv;
    int tid = threadIdx.x;
    unsigned t = blockIdx.x * 1024u + tid;
    int i = (int)(t >> 4), w = (int)(t & 15u);
    if (i < TOPK) {
        float x1 = boxK[i * 4 + 0], y1 = boxK[i * 4 + 1];
        float x2 = boxK[i * 4 + 2], y2 = boxK[i * 4 + 3];
        int ci = clsK[i];
        float ai = (x2 - x1) * (y2 - y1);
        u64 m = 0;
        int jbase = w << 6;
        for (int jj = 0; jj < 64; jj++) {
            int j = jbase + jj;
            if (j >= TOPK) break;
            float u1 = boxK[j * 4 + 0], w1 = boxK[j * 4 + 1];
            float u2 = boxK[j * 4 + 2], w2 = boxK[j * 4 + 3];
            float aj = (u2 - u1) * (w2 - w1);
            float ww = fmaxf(fminf(x2, u2) - fmaxf(x1, u1), 0.0f);
            float hh = fmaxf(fminf(y2, w2) - fmaxf(y1, w1), 0.0f);
            float inter = ww * hh;
            float iou = inter / (ai + aj - inter + 1e-9f);
            if (iou > 0.5f && ci == clsK[j]) m |= (1ull << jj);
        }
        mask[(size_t)i * 16 + w] = m;
    }
    __threadfence();
    __syncthreads();
    if (tid == 0) lastv = atomicAdd(done2, 1u);
    __syncthreads();
    if (lastv != gridDim.x - 1) return;
    // ================= NMS (last block only) =================
    __threadfence();
    int wv = tid >> 6, ln = tid & 63;
    bool valid = (tid < TOPK) && (scoreK[tid] > 0.0f);
    u64 row[16];
    #pragma unroll
    for (int q = 0; q < 16; q++)
        row[q] = (tid < TOPK) ? mask[(size_t)tid * 16 + q] : 0ull;
    u64 lowmask = (1ull << ln) - 1ull;
    bool keep = valid;
    for (int it = 0; it < 1024; ++it) {
        u64 b = __ballot(keep);
        if (ln == 0) words[wv] = b;
        if (tid == 0) changed = 0;
        __syncthreads();
        u64 sup = 0;
        for (int q = 0; q <= wv; q++) {          // wv is wave-uniform
            u64 kw = words[q];
            if (q == wv) kw &= lowmask;
            sup |= row[q] & kw;
        }
        bool nk = valid && (sup == 0ull);
        if (nk != keep) changed = 1;
        keep = nk;
        __syncthreads();
        if (!changed) break;
    }
    if (tid < TOPK) {
        float x1 = boxK[tid * 4 + 0], y1 = boxK[tid * 4 + 1];
        float x2 = boxK[tid * 4 + 2], y2 = boxK[tid * 4 + 3];
        float sc = scoreK[tid];
        out[tid * 5 + 0] = keep ? x1 : 0.0f;
        out[tid * 5 + 1] = keep ? y1 : 0.0f;
        out[tid * 5 + 2] = keep ? x2 : 0.0f;
        out[tid * 5 + 3] = keep ? y2 : 0.0f;
        out[tid * 5 + 4] = keep ? sc : 0.0f;
    }
}

extern "C" void kernel_launch(void* const* d_in, const int* in_sizes, int n_in,
                              void* d_out, int out_size, void* d_ws, size_t ws_size,
                              hipStream_t stream) {
    const float* logits = (const float*)d_in[0];
    const float* boxes  = (const float*)d_in[1];
    float* out = (float*)d_out;
    int nrows = in_sizes[0] / N_CLS;   // 200000

    char* w = (char*)d_ws;
    unsigned* cnt    = (unsigned*)(w + OFF_CNT);
    unsigned* cnt2   = (unsigned*)(w + OFF_CNT2);
    unsigned* done   = (unsigned*)(w + OFF_DONE);
    unsigned* done2  = (unsigned*)(w + OFF_DONE2);
    unsigned* ghist  = (unsigned*)(w + OFF_GH);
    unsigned* rhist  = (unsigned*)(w + OFF_RH);
    u64* sel         = (u64*)(w + OFF_SEL);
    u64* sel2        = (u64*)(w + OFF_SEL2);
    float* boxK      = (float*)(w + OFF_BOX);
    float* scoreK    = (float*)(w + OFF_SCORE);
    int* clsK        = (int*)(w + OFF_CLS);
    u64* mask        = (u64*)(w + OFF_MASK);

    hipMemsetAsync(w, 0, MEMSET_BYTES, stream);

    k_pass1<<<2048, 256, 0, stream>>>(logits, nrows, sel, cnt, ghist);
    k_select<<<256, 256, 0, stream>>>(sel, cnt, ghist, rhist, sel2, cnt2,
                                      done, boxes, boxK, scoreK, clsK);
    k_conflict_nms<<<16, 1024, 0, stream>>>(boxK, scoreK, clsK, mask, done2, out);
}

// Round 6
// 313.817 us; speedup vs baseline: 1.5979x; 1.5979x over previous
//
#include <hip/hip_runtime.h>
#include <stdint.h>
#include <math.h>

#define N_CLS    81
#define TOPK     1000
#define LISTCAP  (1u << 21)     // 2M candidate keys (16 MB)
#define CAP2     65536          // coarse-selected capacity
#define CANDCAP  3072           // exact-threshold candidates held in LDS
#define CSLOTS   12             // CANDCAP / 256
#define SCORE_TH 0.05f
#define IMG_W    1333.0f
#define IMG_H    800.0f
#define GH_REP   16             // coarse-hist replicas (atomic spread)

// coarse bucket = float_bits >> 19; ghist index = (bits>>19) - GH_BASE in [0,128)
#define GH_BASE  1905

// workspace layout (byte offsets)
#define OFF_CNT    0                       // u32 total candidates
#define OFF_CNT2   4                       // u32 coarse-selected count
#define OFF_DONE   8                       // u32 select done-counter
#define OFF_DONE2  12                      // u32 conflict done-counter
#define OFF_GH     64                      // u32[GH_REP][128] coarse hist (8192 B)
#define OFF_RH     8256                    // u32[1024] refined hist
#define MEMSET_BYTES 12352
#define OFF_SEL    12352                   // u64[LISTCAP]
#define OFF_SEL2   16789568                // u64[CAP2]
#define OFF_BOX    17313856                // f32[1000*4]
#define OFF_SCORE  17329856                // f32[1000]
#define OFF_CLS    17333856                // i32[1000]
#define OFF_MASK   17337856                // u64[1024 x 16] conflict bit matrix

typedef unsigned long long u64;

// ------- K1: single pass: softmax, coarse hist (LDS), compact all p>0.05 -------
// NOTE: score arithmetic (lane mapping, butterfly order, expf, e/s) must stay
// bit-identical to rounds 1-5 (absmax 0.0).
__global__ __launch_bounds__(256) void k_pass1(
        const float* __restrict__ logits, int nrows,
        u64* __restrict__ sel, unsigned* __restrict__ cnt,
        unsigned* __restrict__ ghist) {
    __shared__ unsigned lh[128];
    __shared__ u64 cbuf[1024];
    __shared__ __align__(16) float stage[4][328];   // per-wave 4-row stage (324 used)
    __shared__ unsigned lcnt, gbase;
    int tid = threadIdx.x, wv = tid >> 6, ln = tid & 63;
    for (int i = tid; i < 128; i += 256) lh[i] = 0;
    if (tid == 0) lcnt = 0;
    __syncthreads();

    int stride = gridDim.x * 16;
    for (int base = blockIdx.x * 16 + wv * 4; base < nrows; base += stride) {
        int nr = nrows - base; if (nr > 4) nr = 4;   // wave-uniform
        float v0[4], v1[4], m[4], e0[4], e1[4], s[4];
        if (nr == 4) {
            // 4 consecutive rows = 324 floats = 81 float4 (base%4==0 -> 16B aligned)
            const float4* rp4 = (const float4*)(logits + (size_t)base * N_CLS);
            float4 a = rp4[ln];
            float4 b;
            if (ln < 17) b = rp4[64 + ln];
            *((float4*)&stage[wv][ln * 4]) = a;
            if (ln < 17) *((float4*)&stage[wv][256 + ln * 4]) = b;
            __builtin_amdgcn_wave_barrier();   // pin ds_write before ds_read
            #pragma unroll
            for (int k = 0; k < 4; k++) {
                v0[k] = stage[wv][k * 81 + ln];
                v1[k] = (ln < N_CLS - 64) ? stage[wv][k * 81 + 64 + ln] : -INFINITY;
            }
        } else {
            #pragma unroll
            for (int k = 0; k < 4; k++) {
                bool ok = (k < nr);
                const float* rp = logits + (size_t)(ok ? base + k : base) * N_CLS;
                v0[k] = ok ? rp[ln] : 0.0f;
                v1[k] = (ok && ln < N_CLS - 64) ? rp[64 + ln] : -INFINITY;
            }
        }
        #pragma unroll
        for (int k = 0; k < 4; k++) m[k] = fmaxf(v0[k], v1[k]);
        #pragma unroll
        for (int off = 32; off > 0; off >>= 1)
            #pragma unroll
            for (int k = 0; k < 4; k++) m[k] = fmaxf(m[k], __shfl_xor(m[k], off));
        #pragma unroll
        for (int k = 0; k < 4; k++) {
            e0[k] = expf(v0[k] - m[k]);
            e1[k] = (ln < N_CLS - 64) ? expf(v1[k] - m[k]) : 0.0f;
            s[k] = e0[k] + e1[k];
        }
        #pragma unroll
        for (int off = 32; off > 0; off >>= 1)
            #pragma unroll
            for (int k = 0; k < 4; k++) s[k] += __shfl_xor(s[k], off);

        #pragma unroll
        for (int k = 0; k < 4; k++) {
            if (k >= nr) break;                     // wave-uniform
            float p0 = e0[k] / s[k];
            float p1 = e1[k] / s[k];
            bool c0 = (ln != 0) && (p0 > SCORE_TH);
            bool c1 = (ln < N_CLS - 64) && (p1 > SCORE_TH);
            unsigned fb0 = __float_as_uint(p0), fb1 = __float_as_uint(p1);
            if (c0) atomicAdd(&lh[(fb0 >> 19) - GH_BASE], 1u);
            if (c1) atomicAdd(&lh[(fb1 >> 19) - GH_BASE], 1u);
            u64 b0 = __ballot(c0), b1 = __ballot(c1);
            int n0 = __popcll(b0), n1 = __popcll(b1);
            if (n0 + n1 == 0) continue;
            unsigned wb = 0;
            if (ln == 0) wb = atomicAdd(&lcnt, (unsigned)(n0 + n1));
            wb = __shfl(wb, 0);
            u64 lt = (1ull << ln) - 1ull;
            unsigned flat = (unsigned)(base + k) * N_CLS + (unsigned)ln;
            if (c0) {
                unsigned pos = wb + (unsigned)__popcll(b0 & lt);
                u64 key = ((u64)fb0 << 32) | (u64)(0xFFFFFFu - flat);
                if (pos < 1024) cbuf[pos] = key;
                else { unsigned gp = atomicAdd(cnt, 1u); if (gp < LISTCAP) sel[gp] = key; }
            }
            if (c1) {
                unsigned pos = wb + (unsigned)n0 + (unsigned)__popcll(b1 & lt);
                u64 key = ((u64)fb1 << 32) | (u64)(0xFFFFFFu - (flat + 64u));
                if (pos < 1024) cbuf[pos] = key;
                else { unsigned gp = atomicAdd(cnt, 1u); if (gp < LISTCAP) sel[gp] = key; }
            }
        }
    }
    __syncthreads();
    unsigned* gh = ghist + (blockIdx.x & (GH_REP - 1)) * 128;
    for (int i = tid; i < 128; i += 256) {
        unsigned v = lh[i];
        if (v) atomicAdd(&gh[i], v);
    }
    unsigned total = lcnt; if (total > 1024u) total = 1024u;
    if (tid == 0) gbase = atomicAdd(cnt, total);
    __syncthreads();
    unsigned gb = gbase;
    for (unsigned i = tid; i < total; i += 256) {
        unsigned gp = gb + i;
        if (gp < LISTCAP) sel[gp] = cbuf[i];
    }
}

// ------- K2: coarse select + refined hist; LAST block finishes:
//             exact threshold -> filter -> rank (register-resident, static
//             indexing only!) -> decode to boxK/scoreK/clsK -------
__global__ __launch_bounds__(256) void k_select(
        const u64* __restrict__ sel, const unsigned* __restrict__ cnt,
        const unsigned* __restrict__ ghist, unsigned* __restrict__ rhist,
        u64* __restrict__ sel2, unsigned* __restrict__ cnt2,
        unsigned* __restrict__ done, const float* __restrict__ boxes,
        float* __restrict__ boxK, float* __restrict__ scoreK, int* __restrict__ clsK) {
    __shared__ unsigned lh[1024];
    __shared__ unsigned sa[256], sb_[256];
    __shared__ int sB, sG;
    __shared__ unsigned misc;
    __shared__ u64 cand[CANDCAP];
    __shared__ u64 sortedL[TOPK];
    int tid = threadIdx.x, ln = tid & 63;

    // ---- coarse bucket B from replicated global hist ----
    for (int i = tid; i < 1024; i += 256) lh[i] = 0;
    if (tid < 128) {
        unsigned c = 0;
        #pragma unroll
        for (int r = 0; r < GH_REP; r++) c += ghist[r * 128 + tid];
        sa[tid] = c;
    }
    if (tid == 0) sB = -1;
    __syncthreads();
    unsigned *s0 = sa, *s1 = sb_;
    for (int off = 1; off < 128; off <<= 1) {
        if (tid < 128) s1[tid] = s0[tid] + ((tid + off < 128) ? s0[tid + off] : 0u);
        __syncthreads();
        unsigned* t = s0; s0 = s1; s1 = t;
    }
    if (tid < 128 && s0[tid] >= TOPK) atomicMax(&sB, tid);
    __syncthreads();
    int B = sB;
    unsigned c_above = (B >= 0 && B < 127) ? s0[B + 1] : 0u;
    unsigned tbc = (B >= 0) ? ((unsigned)(B + GH_BASE) << 19) : 0u;
    unsigned Bb = (unsigned)(B + GH_BASE);
    __syncthreads();

    // ---- scan candidate list: coarse select + refined hist ----
    unsigned M = *cnt; if (M > LISTCAP) M = LISTCAP;
    unsigned gstride = gridDim.x * 256u;
    for (unsigned ib = blockIdx.x * 256u; ib < M; ib += gstride) {
        unsigned i = ib + tid;
        bool act = (i < M);
        u64 key = act ? sel[i] : 0ull;
        unsigned bits = (unsigned)(key >> 32);
        bool c = act && (bits >= tbc);
        if (c && B >= 0 && (bits >> 19) == Bb)
            atomicAdd(&lh[(bits >> 9) & 1023u], 1u);
        u64 bal = __ballot(c);
        int n = __popcll(bal);
        if (n) {
            unsigned wb = 0;
            if (ln == 0) wb = atomicAdd(cnt2, (unsigned)n);
            wb = __shfl(wb, 0);
            if (c) {
                unsigned pos = wb + (unsigned)__popcll(bal & ((1ull << ln) - 1ull));
                if (pos < CAP2) sel2[pos] = key;
            }
        }
    }
    __syncthreads();
    for (int i = tid; i < 1024; i += 256) {
        unsigned v = lh[i];
        if (v) atomicAdd(&rhist[i], v);
    }
    __threadfence();
    __syncthreads();
    if (tid == 0) misc = atomicAdd(done, 1u);
    __syncthreads();
    if (misc != gridDim.x - 1) return;
    // ================= finisher (last block only) =================
    __threadfence();

    // exact threshold tb from refined hist
    if (tid == 0) sG = -1;
    unsigned ps = 0;
    #pragma unroll
    for (int k = 0; k < 4; k++) ps += rhist[tid * 4 + k];
    sa[tid] = ps;
    __syncthreads();
    s0 = sa; s1 = sb_;
    for (int off = 1; off < 256; off <<= 1) {
        s1[tid] = s0[tid] + ((tid + off < 256) ? s0[tid + off] : 0u);
        __syncthreads();
        unsigned* t = s0; s0 = s1; s1 = t;
    }
    if (B >= 0 && c_above + s0[tid] >= TOPK) atomicMax(&sG, tid);
    __syncthreads();
    if (tid == 0) {
        unsigned tb = 0;
        if (B >= 0) {
            int g = sG;
            int sbin = 0;
            if (g >= 0) {
                unsigned cab = c_above + ((g < 255) ? s0[g + 1] : 0u);
                for (int i = g * 4 + 3; i >= g * 4; --i) {
                    unsigned c = rhist[i];
                    if (cab + c >= TOPK) { sbin = i; break; }
                    cab += c;
                }
            }
            tb = ((unsigned)(B + GH_BASE) << 19) | ((unsigned)sbin << 9);
        }
        misc = tb;
    }
    __syncthreads();
    unsigned tb = misc;
    __syncthreads();

    // filter keys >= tb into LDS cand
    unsigned S = *cnt2; if (S > CAP2) S = CAP2;
    if (tid == 0) misc = 0;
    __syncthreads();
    for (unsigned i = tid; i < S; i += 256) {
        u64 key = sel2[i];
        if ((unsigned)(key >> 32) >= tb) {
            unsigned p = atomicAdd(&misc, 1u);
            if (p < CANDCAP) cand[p] = key;
        }
    }
    for (int i = tid; i < TOPK; i += 256) sortedL[i] = 0ull;
    __syncthreads();
    unsigned C = misc; if (C > CANDCAP) C = CANDCAP;

    // rank by counting: STATIC register slots only (no dynamic array indexing —
    // dynamic indexing demotes to scratch and cost 300 us in round 5).
    u64 my[CSLOTS];
    unsigned r[CSLOTS];
    #pragma unroll
    for (int q = 0; q < CSLOTS; q++) {
        unsigned idx = (unsigned)tid + (unsigned)q * 256u;
        my[q] = (idx < C) ? cand[idx] : 0ull;
        r[q] = 0;
    }
    for (unsigned j = 0; j < C; j++) {
        u64 kj = cand[j];   // broadcast read, conflict-free
        #pragma unroll
        for (int q = 0; q < CSLOTS; q++) r[q] += (kj > my[q]) ? 1u : 0u;
    }
    #pragma unroll
    for (int q = 0; q < CSLOTS; q++) {
        unsigned idx = (unsigned)tid + (unsigned)q * 256u;
        if (idx < C && r[q] < TOPK) sortedL[r[q]] = my[q];
    }
    __syncthreads();

    // decode + clip to global boxK/scoreK/clsK
    for (int t = tid; t < TOPK; t += 256) {
        u64 key = sortedL[t];
        if (key != 0ull) {
            float sc = __uint_as_float((unsigned)(key >> 32));
            unsigned fi = 0xFFFFFFu - (unsigned)(key & 0xFFFFFFFFull);
            unsigned prop = fi / N_CLS;
            int cls = (int)(fi - prop * N_CLS);
            const float* bp = boxes + (size_t)prop * 4;
            boxK[t * 4 + 0] = fminf(fmaxf(bp[0], 0.0f), IMG_W - 1.0f);
            boxK[t * 4 + 1] = fminf(fmaxf(bp[1], 0.0f), IMG_H - 1.0f);
            boxK[t * 4 + 2] = fminf(fmaxf(bp[2], 0.0f), IMG_W - 1.0f);
            boxK[t * 4 + 3] = fminf(fmaxf(bp[3], 0.0f), IMG_H - 1.0f);
            scoreK[t] = sc;
            clsK[t] = cls;
        } else {
            boxK[t * 4 + 0] = 0.0f; boxK[t * 4 + 1] = 0.0f;
            boxK[t * 4 + 2] = 0.0f; boxK[t * 4 + 3] = 0.0f;
            scoreK[t] = 0.0f;
            clsK[t] = -1;
        }
    }
}

// ------- K3: conflict bit-matrix; LAST block runs greedy NMS + writes output -------
__global__ __launch_bounds__(1024) void k_conflict_nms(
        const float* __restrict__ boxK, const float* __restrict__ scoreK,
        const int* __restrict__ clsK, u64* __restrict__ mask,
        unsigned* __restrict__ done2, float* __restrict__ out) {
    __shared__ u64 words[16];
    __shared__ int changed;
    __shared__ unsigned lastv;
    int tid = threadIdx.x;
    unsigned t = blockIdx.x * 1024u + tid;
    int i = (int)(t >> 4), w = (int)(t & 15u);
    if (i < TOPK) {
        float x1 = boxK[i * 4 + 0], y1 = boxK[i * 4 + 1];
        float x2 = boxK[i * 4 + 2], y2 = boxK[i * 4 + 3];
        int ci = clsK[i];
        float ai = (x2 - x1) * (y2 - y1);
        u64 m = 0;
        int jbase = w << 6;
        for (int jj = 0; jj < 64; jj++) {
            int j = jbase + jj;
            if (j >= TOPK) break;
            float u1 = boxK[j * 4 + 0], w1 = boxK[j * 4 + 1];
            float u2 = boxK[j * 4 + 2], w2 = boxK[j * 4 + 3];
            float aj = (u2 - u1) * (w2 - w1);
            float ww = fmaxf(fminf(x2, u2) - fmaxf(x1, u1), 0.0f);
            float hh = fmaxf(fminf(y2, w2) - fmaxf(y1, w1), 0.0f);
            float inter = ww * hh;
            float iou = inter / (ai + aj - inter + 1e-9f);
            if (iou > 0.5f && ci == clsK[j]) m |= (1ull << jj);
        }
        mask[(size_t)i * 16 + w] = m;
    }
    __threadfence();
    __syncthreads();
    if (tid == 0) lastv = atomicAdd(done2, 1u);
    __syncthreads();
    if (lastv != gridDim.x - 1) return;
    // ================= NMS (last block only) =================
    __threadfence();
    int wv = tid >> 6, ln = tid & 63;
    bool valid = (tid < TOPK) && (scoreK[tid] > 0.0f);
    u64 row[16];
    #pragma unroll
    for (int q = 0; q < 16; q++)
        row[q] = (tid < TOPK) ? mask[(size_t)tid * 16 + q] : 0ull;
    u64 lowmask = (1ull << ln) - 1ull;
    bool keep = valid;
    for (int it = 0; it < 1024; ++it) {
        u64 b = __ballot(keep);
        if (ln == 0) words[wv] = b;
        if (tid == 0) changed = 0;
        __syncthreads();
        u64 sup = 0;
        #pragma unroll
        for (int q = 0; q < 16; q++) {   // STATIC index; predicate on q vs wv
            u64 kw = words[q];
            kw = (q < wv) ? kw : ((q == wv) ? (kw & lowmask) : 0ull);
            sup |= row[q] & kw;
        }
        bool nk = valid && (sup == 0ull);
        if (nk != keep) changed = 1;
        keep = nk;
        __syncthreads();
        if (!changed) break;
    }
    if (tid < TOPK) {
        float x1 = boxK[tid * 4 + 0], y1 = boxK[tid * 4 + 1];
        float x2 = boxK[tid * 4 + 2], y2 = boxK[tid * 4 + 3];
        float sc = scoreK[tid];
        out[tid * 5 + 0] = keep ? x1 : 0.0f;
        out[tid * 5 + 1] = keep ? y1 : 0.0f;
        out[tid * 5 + 2] = keep ? x2 : 0.0f;
        out[tid * 5 + 3] = keep ? y2 : 0.0f;
        out[tid * 5 + 4] = keep ? sc : 0.0f;
    }
}

extern "C" void kernel_launch(void* const* d_in, const int* in_sizes, int n_in,
                              void* d_out, int out_size, void* d_ws, size_t ws_size,
                              hipStream_t stream) {
    const float* logits = (const float*)d_in[0];
    const float* boxes  = (const float*)d_in[1];
    float* out = (float*)d_out;
    int nrows = in_sizes[0] / N_CLS;   // 200000

    char* w = (char*)d_ws;
    unsigned* cnt    = (unsigned*)(w + OFF_CNT);
    unsigned* cnt2   = (unsigned*)(w + OFF_CNT2);
    unsigned* done   = (unsigned*)(w + OFF_DONE);
    unsigned* done2  = (unsigned*)(w + OFF_DONE2);
    unsigned* ghist  = (unsigned*)(w + OFF_GH);
    unsigned* rhist  = (unsigned*)(w + OFF_RH);
    u64* sel         = (u64*)(w + OFF_SEL);
    u64* sel2        = (u64*)(w + OFF_SEL2);
    float* boxK      = (float*)(w + OFF_BOX);
    float* scoreK    = (float*)(w + OFF_SCORE);
    int* clsK        = (int*)(w + OFF_CLS);
    u64* mask        = (u64*)(w + OFF_MASK);

    hipMemsetAsync(w, 0, MEMSET_BYTES, stream);

    k_pass1<<<2048, 256, 0, stream>>>(logits, nrows, sel, cnt, ghist);
    k_select<<<256, 256, 0, stream>>>(sel, cnt, ghist, rhist, sel2, cnt2,
                                      done, boxes, boxK, scoreK, clsK);
    k_conflict_nms<<<16, 1024, 0, stream>>>(boxK, scoreK, clsK, mask, done2, out);
}

// Round 7
// 269.311 us; speedup vs baseline: 1.8620x; 1.1653x over previous
//
#include <hip/hip_runtime.h>
#include <stdint.h>
#include <math.h>

#define N_CLS    81
#define TOPK     1000
#define LISTCAP  (1u << 21)     // 2M candidate keys (16 MB)
#define CAP2     65536          // coarse-selected capacity
#define CANDCAP  2048           // exact-threshold candidates held in LDS
#define SCORE_TH 0.05f
#define IMG_W    1333.0f
#define IMG_H    800.0f
#define GH_REP   16             // coarse-hist replicas (atomic spread)
#define TAIL_GRID 64

// coarse bucket = float_bits >> 19; ghist index = (bits>>19) - GH_BASE in [0,128)
#define GH_BASE  1905

// workspace layout (byte offsets)
#define OFF_CNT    0                       // u32 total candidates
#define OFF_CNT2   4                       // u32 coarse-selected count
#define OFF_DONE   8                       // u32 scan done-counter
#define OFF_DONE2  12                      // u32 conflict done-counter
#define OFF_FLAG   16                      // u32 "sorted ready" flag
#define OFF_GH     64                      // u32[GH_REP][128] coarse hist (8192 B)
#define OFF_RH     8256                    // u32[1024] refined hist
#define MEMSET_BYTES 12352
#define OFF_SEL    12352                   // u64[LISTCAP]
#define OFF_SEL2   16789568                // u64[CAP2]
#define OFF_BOX    17313856                // f32[1000*4]
#define OFF_SCORE  17329856                // f32[1000]
#define OFF_CLS    17333856                // i32[1000]
#define OFF_MASK   17337856                // u64[1024 x 16] conflict bit matrix

typedef unsigned long long u64;

// ------- K1: single pass: softmax, coarse hist (LDS), compact all p>0.05 -------
// NOTE: score arithmetic (lane mapping, butterfly order, expf, e/s) must stay
// bit-identical to rounds 1-6 (absmax 0.0).
__global__ __launch_bounds__(256) void k_pass1(
        const float* __restrict__ logits, int nrows,
        u64* __restrict__ sel, unsigned* __restrict__ cnt,
        unsigned* __restrict__ ghist) {
    __shared__ unsigned lh[128];
    __shared__ u64 cbuf[1024];
    __shared__ __align__(16) float stage[4][328];   // per-wave 4-row stage (324 used)
    __shared__ unsigned lcnt, gbase;
    int tid = threadIdx.x, wv = tid >> 6, ln = tid & 63;
    for (int i = tid; i < 128; i += 256) lh[i] = 0;
    if (tid == 0) lcnt = 0;
    __syncthreads();

    int stride = gridDim.x * 16;
    for (int base = blockIdx.x * 16 + wv * 4; base < nrows; base += stride) {
        int nr = nrows - base; if (nr > 4) nr = 4;   // wave-uniform
        float v0[4], v1[4], m[4], e0[4], e1[4], s[4];
        if (nr == 4) {
            // 4 consecutive rows = 324 floats = 81 float4 (base%4==0 -> 16B aligned)
            const float4* rp4 = (const float4*)(logits + (size_t)base * N_CLS);
            float4 a = rp4[ln];
            float4 b;
            if (ln < 17) b = rp4[64 + ln];
            *((float4*)&stage[wv][ln * 4]) = a;
            if (ln < 17) *((float4*)&stage[wv][256 + ln * 4]) = b;
            __builtin_amdgcn_wave_barrier();   // pin ds_write before ds_read
            #pragma unroll
            for (int k = 0; k < 4; k++) {
                v0[k] = stage[wv][k * 81 + ln];
                v1[k] = (ln < N_CLS - 64) ? stage[wv][k * 81 + 64 + ln] : -INFINITY;
            }
        } else {
            #pragma unroll
            for (int k = 0; k < 4; k++) {
                bool ok = (k < nr);
                const float* rp = logits + (size_t)(ok ? base + k : base) * N_CLS;
                v0[k] = ok ? rp[ln] : 0.0f;
                v1[k] = (ok && ln < N_CLS - 64) ? rp[64 + ln] : -INFINITY;
            }
        }
        #pragma unroll
        for (int k = 0; k < 4; k++) m[k] = fmaxf(v0[k], v1[k]);
        #pragma unroll
        for (int off = 32; off > 0; off >>= 1)
            #pragma unroll
            for (int k = 0; k < 4; k++) m[k] = fmaxf(m[k], __shfl_xor(m[k], off));
        #pragma unroll
        for (int k = 0; k < 4; k++) {
            e0[k] = expf(v0[k] - m[k]);
            e1[k] = (ln < N_CLS - 64) ? expf(v1[k] - m[k]) : 0.0f;
            s[k] = e0[k] + e1[k];
        }
        #pragma unroll
        for (int off = 32; off > 0; off >>= 1)
            #pragma unroll
            for (int k = 0; k < 4; k++) s[k] += __shfl_xor(s[k], off);

        #pragma unroll
        for (int k = 0; k < 4; k++) {
            if (k >= nr) break;                     // wave-uniform
            float p0 = e0[k] / s[k];
            float p1 = e1[k] / s[k];
            bool c0 = (ln != 0) && (p0 > SCORE_TH);
            bool c1 = (ln < N_CLS - 64) && (p1 > SCORE_TH);
            unsigned fb0 = __float_as_uint(p0), fb1 = __float_as_uint(p1);
            if (c0) atomicAdd(&lh[(fb0 >> 19) - GH_BASE], 1u);
            if (c1) atomicAdd(&lh[(fb1 >> 19) - GH_BASE], 1u);
            u64 b0 = __ballot(c0), b1 = __ballot(c1);
            int n0 = __popcll(b0), n1 = __popcll(b1);
            if (n0 + n1 == 0) continue;
            unsigned wb = 0;
            if (ln == 0) wb = atomicAdd(&lcnt, (unsigned)(n0 + n1));
            wb = __shfl(wb, 0);
            u64 lt = (1ull << ln) - 1ull;
            unsigned flat = (unsigned)(base + k) * N_CLS + (unsigned)ln;
            if (c0) {
                unsigned pos = wb + (unsigned)__popcll(b0 & lt);
                u64 key = ((u64)fb0 << 32) | (u64)(0xFFFFFFu - flat);
                if (pos < 1024) cbuf[pos] = key;
                else { unsigned gp = atomicAdd(cnt, 1u); if (gp < LISTCAP) sel[gp] = key; }
            }
            if (c1) {
                unsigned pos = wb + (unsigned)n0 + (unsigned)__popcll(b1 & lt);
                u64 key = ((u64)fb1 << 32) | (u64)(0xFFFFFFu - (flat + 64u));
                if (pos < 1024) cbuf[pos] = key;
                else { unsigned gp = atomicAdd(cnt, 1u); if (gp < LISTCAP) sel[gp] = key; }
            }
        }
    }
    __syncthreads();
    unsigned* gh = ghist + (blockIdx.x & (GH_REP - 1)) * 128;
    for (int i = tid; i < 128; i += 256) {
        unsigned v = lh[i];
        if (v) atomicAdd(&gh[i], v);
    }
    unsigned total = lcnt; if (total > 1024u) total = 1024u;
    if (tid == 0) gbase = atomicAdd(cnt, total);
    __syncthreads();
    unsigned gb = gbase;
    for (unsigned i = tid; i < total; i += 256) {
        unsigned gp = gb + i;
        if (gp < LISTCAP) sel[gp] = cbuf[i];
    }
}

// ------- K2: fused tail. Phases:
//  (all 64 blocks)  coarse-B, scan sel -> sel2 + refined hist, done-counter
//  (last block)     exact tb -> filter -> rank(1024 thr, 2 slots) -> decode ->
//                   boxK/scoreK/clsK global -> set flag
//  (blocks 0..15)   s_sleep-wait on flag -> copy table to LDS -> conflict matrix
//  (last of 16)     Jacobi greedy-NMS fixed point -> write output
__global__ __launch_bounds__(1024) void k_tail(
        const u64* __restrict__ sel, const unsigned* __restrict__ cnt,
        const unsigned* __restrict__ ghist, unsigned* __restrict__ rhist,
        u64* __restrict__ sel2, unsigned* __restrict__ cnt2,
        unsigned* __restrict__ done, unsigned* __restrict__ done2,
        unsigned* __restrict__ flag,
        const float* __restrict__ boxes,
        float* __restrict__ boxK, float* __restrict__ scoreK, int* __restrict__ clsK,
        u64* __restrict__ mask, float* __restrict__ out) {
    __shared__ unsigned lh[1024];
    __shared__ unsigned sa[1024], sbv[1024];
    __shared__ int sB, sG;
    __shared__ unsigned misc;
    __shared__ u64 cand[CANDCAP];
    __shared__ u64 sortedL[TOPK];
    __shared__ float4 boxL[TOPK];
    __shared__ float scoreL[TOPK];
    __shared__ int clsL[TOPK];
    __shared__ u64 words[16];
    __shared__ int changed;

    int tid = threadIdx.x, bid = blockIdx.x, ln = tid & 63;

    // ---- coarse bucket B (per-block, redundant; 8 KB read) ----
    lh[tid] = 0;
    if (tid < 128) {
        unsigned c = 0;
        #pragma unroll
        for (int r = 0; r < GH_REP; r++) c += ghist[r * 128 + tid];
        sa[tid] = c;
    }
    if (tid == 0) sB = -1;
    __syncthreads();
    {
        unsigned *s0 = sa, *s1 = sbv;
        for (int off = 1; off < 128; off <<= 1) {
            if (tid < 128) s1[tid] = s0[tid] + ((tid + off < 128) ? s0[tid + off] : 0u);
            __syncthreads();
            unsigned* t = s0; s0 = s1; s1 = t;
        }
        if (tid < 128 && s0[tid] >= TOPK) atomicMax(&sB, tid);
        __syncthreads();
    }
    int B = sB;
    unsigned c_above = 0;
    {   // s0 after 7 steps is sbv (odd # of swaps from sa) — recompute pointer:
        unsigned* s0 = sbv;  // 7 iterations: sa->sbv->sa->... ends at sbv? verify: off=1(sa->sbv),2(sbv->sa),4(sa->sbv),8,16,32,64 -> 7 swaps -> final results in sbv
        c_above = (B >= 0 && B < 127) ? s0[B + 1] : 0u;
    }
    unsigned tbc = (B >= 0) ? ((unsigned)(B + GH_BASE) << 19) : 0u;
    unsigned Bb = (unsigned)(B + GH_BASE);
    __syncthreads();

    // ---- scan sel: coarse select into sel2 + refined LDS hist ----
    unsigned M = *cnt; if (M > LISTCAP) M = LISTCAP;
    unsigned gstride = gridDim.x * 1024u;
    for (unsigned ib = bid * 1024u; ib < M; ib += gstride) {
        unsigned i = ib + tid;
        bool act = (i < M);
        u64 key = act ? sel[i] : 0ull;
        unsigned bits = (unsigned)(key >> 32);
        bool c = act && (bits >= tbc);
        if (c && B >= 0 && (bits >> 19) == Bb)
            atomicAdd(&lh[(bits >> 9) & 1023u], 1u);
        u64 bal = __ballot(c);
        int n = __popcll(bal);
        if (n) {
            unsigned wb = 0;
            if (ln == 0) wb = atomicAdd(cnt2, (unsigned)n);
            wb = __shfl(wb, 0);
            if (c) {
                unsigned pos = wb + (unsigned)__popcll(bal & ((1ull << ln) - 1ull));
                if (pos < CAP2) sel2[pos] = key;
            }
        }
    }
    __syncthreads();
    if (lh[tid]) atomicAdd(&rhist[tid], lh[tid]);
    __threadfence();
    __syncthreads();
    if (tid == 0) misc = atomicAdd(done, 1u);
    __syncthreads();
    bool isLast = (misc == gridDim.x - 1);
    __syncthreads();

    if (isLast) {
        // ================= finisher =================
        __threadfence();
        // exact threshold tb: suffix-sum over 1024 refined bins
        if (tid == 0) sG = -1;
        sa[tid] = rhist[tid];
        __syncthreads();
        unsigned *s0 = sa, *s1 = sbv;
        for (int off = 1; off < 1024; off <<= 1) {
            s1[tid] = s0[tid] + ((tid + off < 1024) ? s0[tid + off] : 0u);
            __syncthreads();
            unsigned* t = s0; s0 = s1; s1 = t;
        }
        if (B >= 0 && c_above + s0[tid] >= TOPK) atomicMax(&sG, tid);
        __syncthreads();
        unsigned tb = 0;
        if (B >= 0) {
            int sbin = sG; if (sbin < 0) sbin = 0;
            tb = ((unsigned)(B + GH_BASE) << 19) | ((unsigned)sbin << 9);
        }
        __syncthreads();

        // filter sel2 keys >= tb into LDS cand
        unsigned S = *cnt2; if (S > CAP2) S = CAP2;
        if (tid == 0) misc = 0;
        __syncthreads();
        for (unsigned i = tid; i < S; i += 1024) {
            u64 key = sel2[i];
            if ((unsigned)(key >> 32) >= tb) {
                unsigned p = atomicAdd(&misc, 1u);
                if (p < CANDCAP) cand[p] = key;
            }
        }
        for (int i = tid; i < TOPK; i += 1024) sortedL[i] = 0ull;
        __syncthreads();
        unsigned C = misc; if (C > CANDCAP) C = CANDCAP;

        // rank by counting: 2 static register slots, j-loop unrolled x4
        u64 my0 = ((unsigned)tid < C) ? cand[tid] : 0ull;
        u64 my1 = ((unsigned)tid + 1024u < C) ? cand[tid + 1024] : 0ull;
        unsigned r0 = 0, r1 = 0;
        unsigned j = 0;
        for (; j + 4 <= C; j += 4) {
            u64 k0 = cand[j], k1 = cand[j + 1], k2 = cand[j + 2], k3 = cand[j + 3];
            r0 += (unsigned)(k0 > my0) + (unsigned)(k1 > my0)
                + (unsigned)(k2 > my0) + (unsigned)(k3 > my0);
            r1 += (unsigned)(k0 > my1) + (unsigned)(k1 > my1)
                + (unsigned)(k2 > my1) + (unsigned)(k3 > my1);
        }
        for (; j < C; ++j) {
            u64 k0 = cand[j];
            r0 += (unsigned)(k0 > my0);
            r1 += (unsigned)(k0 > my1);
        }
        if ((unsigned)tid < C && r0 < TOPK) sortedL[r0] = my0;
        if ((unsigned)tid + 1024u < C && r1 < TOPK) sortedL[r1] = my1;
        __syncthreads();

        // decode + clip -> global table
        if (tid < TOPK) {
            u64 key = sortedL[tid];
            if (key != 0ull) {
                float sc = __uint_as_float((unsigned)(key >> 32));
                unsigned fi = 0xFFFFFFu - (unsigned)(key & 0xFFFFFFFFull);
                unsigned prop = fi / N_CLS;
                int cls = (int)(fi - prop * N_CLS);
                const float* bp = boxes + (size_t)prop * 4;
                boxK[tid * 4 + 0] = fminf(fmaxf(bp[0], 0.0f), IMG_W - 1.0f);
                boxK[tid * 4 + 1] = fminf(fmaxf(bp[1], 0.0f), IMG_H - 1.0f);
                boxK[tid * 4 + 2] = fminf(fmaxf(bp[2], 0.0f), IMG_W - 1.0f);
                boxK[tid * 4 + 3] = fminf(fmaxf(bp[3], 0.0f), IMG_H - 1.0f);
                scoreK[tid] = sc;
                clsK[tid] = cls;
            } else {
                boxK[tid * 4 + 0] = 0.0f; boxK[tid * 4 + 1] = 0.0f;
                boxK[tid * 4 + 2] = 0.0f; boxK[tid * 4 + 3] = 0.0f;
                scoreK[tid] = 0.0f;
                clsK[tid] = -1;
            }
        }
        __threadfence();
        __syncthreads();
        if (tid == 0) atomicExch(flag, 1u);
    }

    if (bid >= 16) return;
    // ---- wait for sorted table ----
    if (tid == 0) {
        while (atomicAdd(flag, 0u) == 0u) __builtin_amdgcn_s_sleep(64);
    }
    __syncthreads();
    __threadfence();

    // copy table into LDS
    if (tid < TOPK) {
        boxL[tid] = *((const float4*)(boxK + tid * 4));
        scoreL[tid] = scoreK[tid];
        clsL[tid] = clsK[tid];
    }
    __syncthreads();

    // conflict word: t in [0, 16384): i = t>>4, w = t&15
    {
        unsigned t = bid * 1024u + tid;
        int i = (int)(t >> 4), w = (int)(t & 15u);
        if (i < TOPK) {
            float4 bi = boxL[i];
            int ci = clsL[i];
            float ai = (bi.z - bi.x) * (bi.w - bi.y);
            u64 m = 0;
            int jbase = w << 6;
            for (int jj = 0; jj < 64; jj++) {
                int jx = jbase + jj;
                if (jx >= TOPK) break;
                float4 bj = boxL[jx];
                float aj = (bj.z - bj.x) * (bj.w - bj.y);
                float ww = fmaxf(fminf(bi.z, bj.z) - fmaxf(bi.x, bj.x), 0.0f);
                float hh = fmaxf(fminf(bi.w, bj.w) - fmaxf(bi.y, bj.y), 0.0f);
                float inter = ww * hh;
                float iou = inter / (ai + aj - inter + 1e-9f);
                if (iou > 0.5f && ci == clsL[jx]) m |= (1ull << jj);
            }
            mask[(size_t)i * 16 + w] = m;
        }
    }
    __threadfence();
    __syncthreads();
    if (tid == 0) misc = atomicAdd(done2, 1u);
    __syncthreads();
    if (misc != 15u) return;
    // ================= NMS (last conflict block) =================
    __threadfence();
    int wv = tid >> 6;
    bool valid = (tid < TOPK) && (scoreL[tid] > 0.0f);
    u64 row[16];
    #pragma unroll
    for (int q = 0; q < 16; q++)
        row[q] = (tid < TOPK) ? mask[(size_t)tid * 16 + q] : 0ull;
    u64 lowmask = (1ull << ln) - 1ull;
    bool keep = valid;
    for (int it = 0; it < 1024; ++it) {
        u64 b = __ballot(keep);
        if (ln == 0) words[wv] = b;
        if (tid == 0) changed = 0;
        __syncthreads();
        u64 sup = 0;
        #pragma unroll
        for (int q = 0; q < 16; q++) {   // static index; predicate on q vs wv
            u64 kw = words[q];
            kw = (q < wv) ? kw : ((q == wv) ? (kw & lowmask) : 0ull);
            sup |= row[q] & kw;
        }
        bool nk = valid && (sup == 0ull);
        if (nk != keep) changed = 1;
        keep = nk;
        __syncthreads();
        if (!changed) break;
    }
    if (tid < TOPK) {
        float4 bb = boxL[tid];
        float sc = scoreL[tid];
        out[tid * 5 + 0] = keep ? bb.x : 0.0f;
        out[tid * 5 + 1] = keep ? bb.y : 0.0f;
        out[tid * 5 + 2] = keep ? bb.z : 0.0f;
        out[tid * 5 + 3] = keep ? bb.w : 0.0f;
        out[tid * 5 + 4] = keep ? sc : 0.0f;
    }
}

extern "C" void kernel_launch(void* const* d_in, const int* in_sizes, int n_in,
                              void* d_out, int out_size, void* d_ws, size_t ws_size,
                              hipStream_t stream) {
    const float* logits = (const float*)d_in[0];
    const float* boxes  = (const float*)d_in[1];
    float* out = (float*)d_out;
    int nrows = in_sizes[0] / N_CLS;   // 200000

    char* w = (char*)d_ws;
    unsigned* cnt    = (unsigned*)(w + OFF_CNT);
    unsigned* cnt2   = (unsigned*)(w + OFF_CNT2);
    unsigned* done   = (unsigned*)(w + OFF_DONE);
    unsigned* done2  = (unsigned*)(w + OFF_DONE2);
    unsigned* flag   = (unsigned*)(w + OFF_FLAG);
    unsigned* ghist  = (unsigned*)(w + OFF_GH);
    unsigned* rhist  = (unsigned*)(w + OFF_RH);
    u64* sel         = (u64*)(w + OFF_SEL);
    u64* sel2        = (u64*)(w + OFF_SEL2);
    float* boxK      = (float*)(w + OFF_BOX);
    float* scoreK    = (float*)(w + OFF_SCORE);
    int* clsK        = (int*)(w + OFF_CLS);
    u64* mask        = (u64*)(w + OFF_MASK);

    hipMemsetAsync(w, 0, MEMSET_BYTES, stream);

    k_pass1<<<2048, 256, 0, stream>>>(logits, nrows, sel, cnt, ghist);
    k_tail<<<TAIL_GRID, 1024, 0, stream>>>(sel, cnt, ghist, rhist, sel2, cnt2,
                                           done, done2, flag, boxes,
                                           boxK, scoreK, clsK, mask, out);
}